// Round 7
// baseline (263.271 us; speedup 1.0000x reference)
//
#include <hip/hip_runtime.h>

#define E_EDGES 131072
// Layer dims: in {2048,4096,4096} -> out {4096,4096,1024}, batch 1024.
// Activations feature-major (hT[feat][1024]); CSR-by-dst built on device with
// no global atomics (LDS histogram -> scan -> LDS-cursor scatter).
// Rows padded to multiples of 16 (zero pads written by padfill_kernel).
// SpMM: block = 512 threads = 8 waves = 8 dst rows x one 128-col chunk;
// chunk = blockIdx&7 -> XCD-resident input/output slices (2 MB each in L2).

#define EPAD01 196608   // capacity, layers 0,1 (4096 rows, E + 16*rows)
#define EPAD2  147456   // capacity, layer 2  (1024 rows)
#define C_CH   16       // chunks per layer (preprocessing)
#define CHUNK  (E_EDGES / C_CH)   // 8192 edges per chunk

typedef int iv4 __attribute__((ext_vector_type(4)));

__global__ void transpose_kernel(const float* __restrict__ in, float* __restrict__ out,
                                 int R, int C) {
  __shared__ float tile[32][33];
  int c0 = blockIdx.x << 5, r0 = blockIdx.y << 5;
  int tx = threadIdx.x, ty = threadIdx.y;  // 32 x 8
#pragma unroll
  for (int i = 0; i < 32; i += 8)
    tile[ty + i][tx] = in[(size_t)(r0 + ty + i) * C + (c0 + tx)];
  __syncthreads();
#pragma unroll
  for (int i = 0; i < 32; i += 8)
    out[(size_t)(c0 + ty + i) * R + (r0 + tx)] = tile[tx][ty + i];
}

// Phase A: per-(layer,chunk) LDS histogram of dst. bid = l*16 + c.
__global__ void __launch_bounds__(256) count_kernel(
    const int* __restrict__ d0, const int* __restrict__ d1, const int* __restrict__ d2,
    int* __restrict__ cntA) {
  int bid = blockIdx.x, l = bid >> 4, c = bid & 15;
  const int* dp = (l == 0) ? d0 : (l == 1) ? d1 : d2;
  __shared__ int hist[4096];
  for (int r = threadIdx.x; r < 4096; r += 256) hist[r] = 0;
  __syncthreads();
  int base = c * CHUNK;
  for (int i = 0; i < CHUNK; i += 256)
    atomicAdd(&hist[dp[base + i + threadIdx.x]], 1);
  __syncthreads();
  for (int r = threadIdx.x; r < 4096; r += 256)
    cntA[(((l << 12) + r) << 4) + c] = hist[r];  // layer2 rows>=1024 stay 0
}

// Phase B: per-layer (blockIdx = l) row totals -> padded row scan.
// rowptr[row] = padded row start; fillstart[row] = start + true count;
// cntA[row][c] rewritten to the chunk's start offset within the row.
__global__ void __launch_bounds__(1024) scan_kernel(int* __restrict__ cntA,
                                                    int* __restrict__ rowptr,
                                                    int* __restrict__ fillstart) {
  int l = blockIdx.x;
  int* rp = rowptr + l * 4104;
  int t = threadIdx.x;  // 1024 threads, 4 rows each
  int tot[4], pad[4];
  int local = 0;
  for (int i = 0; i < 4; ++i) {
    int row = (t << 2) + i;
    const int4* p = (const int4*)(cntA + (((l << 12) + row) << 4));
    int4 a = p[0], b = p[1], cc = p[2], dd = p[3];
    int s = a.x + a.y + a.z + a.w + b.x + b.y + b.z + b.w +
            cc.x + cc.y + cc.z + cc.w + dd.x + dd.y + dd.z + dd.w;
    tot[i] = s;
    pad[i] = (s + 15) & ~15;
    local += pad[i];
  }
  int lane = t & 63, wid = t >> 6;
  int incl = local;
  for (int off = 1; off < 64; off <<= 1) {
    int u = __shfl_up(incl, off, 64);
    if (lane >= off) incl += u;
  }
  __shared__ int wsum[16];
  if (lane == 63) wsum[wid] = incl;
  __syncthreads();
  if (t < 16) {
    int v = wsum[t];
    int iv = v;
    for (int off = 1; off < 16; off <<= 1) {
      int u = __shfl_up(iv, off, 16);
      if (t >= off) iv += u;
    }
    wsum[t] = iv - v;
  }
  __syncthreads();
  int run = wsum[wid] + (incl - local);
  for (int i = 0; i < 4; ++i) {
    int row = (t << 2) + i;
    rp[row] = run;
    fillstart[(l << 12) + row] = run + tot[i];
    int* p = cntA + (((l << 12) + row) << 4);
    int acc = run;
    for (int c = 0; c < 16; ++c) { int v = p[c]; p[c] = acc; acc += v; }
    run += pad[i];
  }
  if (t == 1023) rp[4096] = run;  // also covers rp[n] (rows past n are 0-count)
}

// Phase C: scatter with LDS cursors only. bid = l*16 + c.
__global__ void __launch_bounds__(256) scatter_kernel(
    const int* __restrict__ s0p, const int* __restrict__ d0p, const float* __restrict__ w0p,
    const int* __restrict__ s1p, const int* __restrict__ d1p, const float* __restrict__ w1p,
    const int* __restrict__ s2p, const int* __restrict__ d2p, const float* __restrict__ w2p,
    const int* __restrict__ cntA, int2* __restrict__ edges) {
  int bid = blockIdx.x, l = bid >> 4, c = bid & 15;
  const int* sp = (l == 0) ? s0p : (l == 1) ? s1p : s2p;
  const int* dp = (l == 0) ? d0p : (l == 1) ? d1p : d2p;
  const float* wp = (l == 0) ? w0p : (l == 1) ? w1p : w2p;
  int off = (l == 0) ? 0 : (l == 1) ? EPAD01 : 2 * EPAD01;
  __shared__ int cursor[4096];
  for (int r = threadIdx.x; r < 4096; r += 256)
    cursor[r] = cntA[(((l << 12) + r) << 4) + c];
  __syncthreads();
  int base = c * CHUNK;
  for (int i = 0; i < CHUNK; i += 256) {
    int e = base + i + threadIdx.x;
    int d = dp[e];
    int s = sp[e];
    float wv = wp[e];
    int pos = atomicAdd(&cursor[d], 1);
    edges[off + pos] = make_int2(s, __float_as_int(wv));
  }
}

// Zero the pad slots [fillstart[d], rowptr[d+1]) of every row (<= 15 per row).
__global__ void padfill_kernel(const int* __restrict__ fillstart,
                               const int* __restrict__ rowptr,
                               int2* __restrict__ edges) {
  int i = blockIdx.x * 256 + threadIdx.x;   // 0..12287
  int l = i >> 12, d = i & 4095;
  if (l == 2 && d >= 1024) return;
  int off = (l == 0) ? 0 : (l == 1) ? EPAD01 : 2 * EPAD01;
  int end = rowptr[l * 4104 + d + 1];
  int2 z = make_int2(0, 0);
  for (int p = fillstart[(l << 12) + d]; p < end; ++p) edges[off + p] = z;
}

#define LD2(IDX) (*(const float2*)(hb + ((size_t)(unsigned)(IDX) << 12)))
#define FMA2(A, WB, V) { float _w = __int_as_float(WB); \
  A.x = fmaf(_w, V.x, A.x); A.y = fmaf(_w, V.y, A.y); }

// SpMM gather: 512-thread block = 8 waves; wave w owns dst row 8*rg + w over
// one 128-col chunk (c = blockIdx&7 -> XCD c). 64 lanes x float2 = 512 B per
// gather. 16 gathers in flight per wave; edge stream prefetched (int4 pairs).
__global__ void __launch_bounds__(512) spmm_kernel(const float* __restrict__ hT,
                                                   const int2* __restrict__ edges,
                                                   const int* __restrict__ rowptr,
                                                   const float* __restrict__ bias,
                                                   float* __restrict__ outT) {
  int c = blockIdx.x & 7;
  int rg = blockIdx.x >> 3;
  int w = threadIdx.x >> 6;          // wave id 0..7
  int lane = threadIdx.x & 63;
  int d = (rg << 3) + w;
  int col = (c << 7) + (lane << 1);
  const char* hb = (const char*)(hT + col);
  float2 a0 = {0, 0}, a1 = {0, 0}, a2 = {0, 0}, a3 = {0, 0};
  float2 a4 = {0, 0}, a5 = {0, 0}, a6 = {0, 0}, a7 = {0, 0};
  int s0 = rowptr[d], s1 = rowptr[d + 1];  // multiples of 16
  const iv4* ep = (const iv4*)(edges + s0);
  const iv4* ep_end = (const iv4*)(edges + s1);
  iv4 q0, q1, q2, q3, q4, q5, q6, q7;
  if (ep < ep_end) {
    q0 = ep[0]; q1 = ep[1]; q2 = ep[2]; q3 = ep[3];
    q4 = ep[4]; q5 = ep[5]; q6 = ep[6]; q7 = ep[7];
  }
  while (ep < ep_end) {
    iv4 p0 = q0, p1 = q1, p2 = q2, p3 = q3;
    iv4 p4 = q4, p5 = q5, p6 = q6, p7 = q7;
    ep += 8;
    if (ep < ep_end) {
      q0 = ep[0]; q1 = ep[1]; q2 = ep[2]; q3 = ep[3];
      q4 = ep[4]; q5 = ep[5]; q6 = ep[6]; q7 = ep[7];
    }
    float2 v0 = LD2(p0.x), v1 = LD2(p0.z), v2 = LD2(p1.x), v3 = LD2(p1.z);
    float2 v4 = LD2(p2.x), v5 = LD2(p2.z), v6 = LD2(p3.x), v7 = LD2(p3.z);
    float2 v8 = LD2(p4.x), v9 = LD2(p4.z), v10 = LD2(p5.x), v11 = LD2(p5.z);
    float2 v12 = LD2(p6.x), v13 = LD2(p6.z), v14 = LD2(p7.x), v15 = LD2(p7.z);
    FMA2(a0, p0.y, v0); FMA2(a1, p0.w, v1);
    FMA2(a2, p1.y, v2); FMA2(a3, p1.w, v3);
    FMA2(a4, p2.y, v4); FMA2(a5, p2.w, v5);
    FMA2(a6, p3.y, v6); FMA2(a7, p3.w, v7);
    FMA2(a0, p4.y, v8); FMA2(a1, p4.w, v9);
    FMA2(a2, p5.y, v10); FMA2(a3, p5.w, v11);
    FMA2(a4, p6.y, v12); FMA2(a5, p6.w, v13);
    FMA2(a6, p7.y, v14); FMA2(a7, p7.w, v15);
  }
  float b = bias[d];
  float rx = ((a0.x + a1.x) + (a2.x + a3.x)) + ((a4.x + a5.x) + (a6.x + a7.x));
  float ry = ((a0.y + a1.y) + (a2.y + a3.y)) + ((a4.y + a5.y) + (a6.y + a7.y));
  float2 o;
  o.x = fmaxf(rx + b, 0.f);
  o.y = fmaxf(ry + b, 0.f);
  *(float2*)((char*)outT + (((size_t)d << 12) + ((size_t)col << 2))) = o;
}

extern "C" void kernel_launch(void* const* d_in, const int* in_sizes, int n_in,
                              void* d_out, int out_size, void* d_ws, size_t ws_size,
                              hipStream_t stream) {
  const float* x = (const float*)d_in[0];
  const int* src[3]    = {(const int*)d_in[1], (const int*)d_in[5], (const int*)d_in[9]};
  const int* dst[3]    = {(const int*)d_in[2], (const int*)d_in[6], (const int*)d_in[10]};
  const float* w[3]    = {(const float*)d_in[3], (const float*)d_in[7], (const float*)d_in[11]};
  const float* bias[3] = {(const float*)d_in[4], (const float*)d_in[8], (const float*)d_in[12]};
  float* out = (float*)d_out;

  // Workspace (~37 MB):
  //   buf0 @ 0            : 16 MB (xT, later h2T)
  //   buf1 @ 16 MB        : 16 MB (h1T, later outT)
  //   fillstart @ 32 MB   : 3*4096 ints
  //   rowptr @ +64 KB     : 3*4104 ints
  //   cntA   @ +128 KB    : 3*4096*16 ints (per-(row,chunk) counts/offsets)
  //   edges  @ +1 MB      : (2*EPAD01+EPAD2) int2, padded CSR
  char* ws = (char*)d_ws;
  float* buf0      = (float*)(ws);
  float* buf1      = (float*)(ws + (16u << 20));
  int*   fillstart = (int*)(ws + (32u << 20));
  int*   rowptr    = (int*)(ws + (32u << 20) + 65536u);
  int*   cntA      = (int*)(ws + (32u << 20) + 131072u);
  int2*  edges     = (int2*)(ws + (32u << 20) + (1u << 20));

  dim3 tb(32, 8);
  // x [1024][2048] -> buf0 = xT [2048][1024]
  transpose_kernel<<<dim3(2048 / 32, 1024 / 32), tb, 0, stream>>>(x, buf0, 1024, 2048);

  count_kernel<<<3 * C_CH, 256, 0, stream>>>(dst[0], dst[1], dst[2], cntA);
  scan_kernel<<<3, 1024, 0, stream>>>(cntA, rowptr, fillstart);
  scatter_kernel<<<3 * C_CH, 256, 0, stream>>>(
      src[0], dst[0], w[0], src[1], dst[1], w[1], src[2], dst[2], w[2], cntA, edges);
  padfill_kernel<<<12288 / 256, 256, 0, stream>>>(fillstart, rowptr, edges);

  // layer 0: buf0 (2048x1024) -> buf1 (4096x1024)
  spmm_kernel<<<(4096 / 8) * 8, 512, 0, stream>>>(buf0, edges, rowptr, bias[0], buf1);
  // layer 1: buf1 -> buf0 (4096x1024)
  spmm_kernel<<<(4096 / 8) * 8, 512, 0, stream>>>(buf1, edges + EPAD01, rowptr + 4104, bias[1], buf0);
  // layer 2: buf0 -> buf1 (1024x1024, outT)
  spmm_kernel<<<(1024 / 8) * 8, 512, 0, stream>>>(buf0, edges + 2 * EPAD01, rowptr + 2 * 4104, bias[2], buf1);

  // outT [1024 dst][1024 batch] -> d_out [batch][dst]
  transpose_kernel<<<dim3(1024 / 32, 1024 / 32), tb, 0, stream>>>(buf1, out, 1024, 1024);
}

// Round 8
// 241.242 us; speedup vs baseline: 1.0913x; 1.0913x over previous
//
#include <hip/hip_runtime.h>

#define E_EDGES 131072
// Layer dims: in {2048,4096,4096} -> out {4096,4096,1024}, batch 1024.
// Activations feature-major (hT[feat][1024]); CSR-by-dst built on device with
// no global atomics (LDS histogram -> scan -> LDS-cursor scatter).
// Rows padded to multiples of 16 (zero pads written by padfill_kernel).
// SpMM: 128-thread block = 2 waves = 2 dst rows x one 128-col chunk.
// (R7 post-mortem: 8-wave blocks fragmented wave slots + paid max-of-8 row
// imbalance -> 32% occupancy; 1-wave blocks cap at the ~16 WG/CU slot limit
// -> 56%. 2-wave blocks allow 32 waves/CU with only max-of-2 imbalance.)
// chunk = blockIdx&7 -> XCD-resident input/output slices (2 MB each in L2).

#define EPAD01 196608   // capacity, layers 0,1 (4096 rows, E + 16*rows)
#define EPAD2  147456   // capacity, layer 2  (1024 rows)
#define C_CH   16       // chunks per layer (preprocessing)
#define CHUNK  (E_EDGES / C_CH)   // 8192 edges per chunk

typedef int iv4 __attribute__((ext_vector_type(4)));

__global__ void transpose_kernel(const float* __restrict__ in, float* __restrict__ out,
                                 int R, int C) {
  __shared__ float tile[32][33];
  int c0 = blockIdx.x << 5, r0 = blockIdx.y << 5;
  int tx = threadIdx.x, ty = threadIdx.y;  // 32 x 8
#pragma unroll
  for (int i = 0; i < 32; i += 8)
    tile[ty + i][tx] = in[(size_t)(r0 + ty + i) * C + (c0 + tx)];
  __syncthreads();
#pragma unroll
  for (int i = 0; i < 32; i += 8)
    out[(size_t)(c0 + ty + i) * R + (r0 + tx)] = tile[tx][ty + i];
}

// Phase A: per-(layer,chunk) LDS histogram of dst. bid = l*16 + c.
__global__ void __launch_bounds__(256) count_kernel(
    const int* __restrict__ d0, const int* __restrict__ d1, const int* __restrict__ d2,
    int* __restrict__ cntA) {
  int bid = blockIdx.x, l = bid >> 4, c = bid & 15;
  const int* dp = (l == 0) ? d0 : (l == 1) ? d1 : d2;
  __shared__ int hist[4096];
  for (int r = threadIdx.x; r < 4096; r += 256) hist[r] = 0;
  __syncthreads();
  int base = c * CHUNK;
  for (int i = 0; i < CHUNK; i += 256)
    atomicAdd(&hist[dp[base + i + threadIdx.x]], 1);
  __syncthreads();
  for (int r = threadIdx.x; r < 4096; r += 256)
    cntA[(((l << 12) + r) << 4) + c] = hist[r];  // layer2 rows>=1024 stay 0
}

// Phase B: per-layer (blockIdx = l) row totals -> padded row scan.
// rowptr[row] = padded row start; fillstart[row] = start + true count;
// cntA[row][c] rewritten to the chunk's start offset within the row.
__global__ void __launch_bounds__(1024) scan_kernel(int* __restrict__ cntA,
                                                    int* __restrict__ rowptr,
                                                    int* __restrict__ fillstart) {
  int l = blockIdx.x;
  int* rp = rowptr + l * 4104;
  int t = threadIdx.x;  // 1024 threads, 4 rows each
  int tot[4], pad[4];
  int local = 0;
  for (int i = 0; i < 4; ++i) {
    int row = (t << 2) + i;
    const int4* p = (const int4*)(cntA + (((l << 12) + row) << 4));
    int4 a = p[0], b = p[1], cc = p[2], dd = p[3];
    int s = a.x + a.y + a.z + a.w + b.x + b.y + b.z + b.w +
            cc.x + cc.y + cc.z + cc.w + dd.x + dd.y + dd.z + dd.w;
    tot[i] = s;
    pad[i] = (s + 15) & ~15;
    local += pad[i];
  }
  int lane = t & 63, wid = t >> 6;
  int incl = local;
  for (int off = 1; off < 64; off <<= 1) {
    int u = __shfl_up(incl, off, 64);
    if (lane >= off) incl += u;
  }
  __shared__ int wsum[16];
  if (lane == 63) wsum[wid] = incl;
  __syncthreads();
  if (t < 16) {
    int v = wsum[t];
    int iv = v;
    for (int off = 1; off < 16; off <<= 1) {
      int u = __shfl_up(iv, off, 16);
      if (t >= off) iv += u;
    }
    wsum[t] = iv - v;
  }
  __syncthreads();
  int run = wsum[wid] + (incl - local);
  for (int i = 0; i < 4; ++i) {
    int row = (t << 2) + i;
    rp[row] = run;
    fillstart[(l << 12) + row] = run + tot[i];
    int* p = cntA + (((l << 12) + row) << 4);
    int acc = run;
    for (int c = 0; c < 16; ++c) { int v = p[c]; p[c] = acc; acc += v; }
    run += pad[i];
  }
  if (t == 1023) rp[4096] = run;  // also covers rp[n] (rows past n are 0-count)
}

// Phase C: scatter with LDS cursors only. bid = l*16 + c.
__global__ void __launch_bounds__(256) scatter_kernel(
    const int* __restrict__ s0p, const int* __restrict__ d0p, const float* __restrict__ w0p,
    const int* __restrict__ s1p, const int* __restrict__ d1p, const float* __restrict__ w1p,
    const int* __restrict__ s2p, const int* __restrict__ d2p, const float* __restrict__ w2p,
    const int* __restrict__ cntA, int2* __restrict__ edges) {
  int bid = blockIdx.x, l = bid >> 4, c = bid & 15;
  const int* sp = (l == 0) ? s0p : (l == 1) ? s1p : s2p;
  const int* dp = (l == 0) ? d0p : (l == 1) ? d1p : d2p;
  const float* wp = (l == 0) ? w0p : (l == 1) ? w1p : w2p;
  int off = (l == 0) ? 0 : (l == 1) ? EPAD01 : 2 * EPAD01;
  __shared__ int cursor[4096];
  for (int r = threadIdx.x; r < 4096; r += 256)
    cursor[r] = cntA[(((l << 12) + r) << 4) + c];
  __syncthreads();
  int base = c * CHUNK;
  for (int i = 0; i < CHUNK; i += 256) {
    int e = base + i + threadIdx.x;
    int d = dp[e];
    int s = sp[e];
    float wv = wp[e];
    int pos = atomicAdd(&cursor[d], 1);
    edges[off + pos] = make_int2(s, __float_as_int(wv));
  }
}

// Zero the pad slots [fillstart[d], rowptr[d+1]) of every row (<= 15 per row).
__global__ void padfill_kernel(const int* __restrict__ fillstart,
                               const int* __restrict__ rowptr,
                               int2* __restrict__ edges) {
  int i = blockIdx.x * 256 + threadIdx.x;   // 0..12287
  int l = i >> 12, d = i & 4095;
  if (l == 2 && d >= 1024) return;
  int off = (l == 0) ? 0 : (l == 1) ? EPAD01 : 2 * EPAD01;
  int end = rowptr[l * 4104 + d + 1];
  int2 z = make_int2(0, 0);
  for (int p = fillstart[(l << 12) + d]; p < end; ++p) edges[off + p] = z;
}

#define LD2(IDX) (*(const float2*)(hb + ((size_t)(unsigned)(IDX) << 12)))
#define FMA2(A, WB, V) { float _w = __int_as_float(WB); \
  A.x = fmaf(_w, V.x, A.x); A.y = fmaf(_w, V.y, A.y); }

// SpMM gather: 128-thread block = 2 waves; wave w owns dst row 2*rg + w over
// one 128-col chunk (c = blockIdx&7 -> XCD c). 64 lanes x float2 = 512 B per
// gather, 16 gathers in flight; edge stream prefetched (int4 x8).
__global__ void __launch_bounds__(128) spmm_kernel(const float* __restrict__ hT,
                                                   const int2* __restrict__ edges,
                                                   const int* __restrict__ rowptr,
                                                   const float* __restrict__ bias,
                                                   float* __restrict__ outT) {
  int c = blockIdx.x & 7;
  int rg = blockIdx.x >> 3;
  int w = threadIdx.x >> 6;          // wave id 0..1
  int lane = threadIdx.x & 63;
  int d = (rg << 1) + w;
  int col = (c << 7) + (lane << 1);
  const char* hb = (const char*)(hT + col);
  float2 a0 = {0, 0}, a1 = {0, 0}, a2 = {0, 0}, a3 = {0, 0};
  float2 a4 = {0, 0}, a5 = {0, 0}, a6 = {0, 0}, a7 = {0, 0};
  int s0 = rowptr[d], s1 = rowptr[d + 1];  // multiples of 16
  const iv4* ep = (const iv4*)(edges + s0);
  const iv4* ep_end = (const iv4*)(edges + s1);
  iv4 q0, q1, q2, q3, q4, q5, q6, q7;
  if (ep < ep_end) {
    q0 = ep[0]; q1 = ep[1]; q2 = ep[2]; q3 = ep[3];
    q4 = ep[4]; q5 = ep[5]; q6 = ep[6]; q7 = ep[7];
  }
  while (ep < ep_end) {
    iv4 p0 = q0, p1 = q1, p2 = q2, p3 = q3;
    iv4 p4 = q4, p5 = q5, p6 = q6, p7 = q7;
    ep += 8;
    if (ep < ep_end) {
      q0 = ep[0]; q1 = ep[1]; q2 = ep[2]; q3 = ep[3];
      q4 = ep[4]; q5 = ep[5]; q6 = ep[6]; q7 = ep[7];
    }
    float2 v0 = LD2(p0.x), v1 = LD2(p0.z), v2 = LD2(p1.x), v3 = LD2(p1.z);
    float2 v4 = LD2(p2.x), v5 = LD2(p2.z), v6 = LD2(p3.x), v7 = LD2(p3.z);
    float2 v8 = LD2(p4.x), v9 = LD2(p4.z), v10 = LD2(p5.x), v11 = LD2(p5.z);
    float2 v12 = LD2(p6.x), v13 = LD2(p6.z), v14 = LD2(p7.x), v15 = LD2(p7.z);
    FMA2(a0, p0.y, v0); FMA2(a1, p0.w, v1);
    FMA2(a2, p1.y, v2); FMA2(a3, p1.w, v3);
    FMA2(a4, p2.y, v4); FMA2(a5, p2.w, v5);
    FMA2(a6, p3.y, v6); FMA2(a7, p3.w, v7);
    FMA2(a0, p4.y, v8); FMA2(a1, p4.w, v9);
    FMA2(a2, p5.y, v10); FMA2(a3, p5.w, v11);
    FMA2(a4, p6.y, v12); FMA2(a5, p6.w, v13);
    FMA2(a6, p7.y, v14); FMA2(a7, p7.w, v15);
  }
  float b = bias[d];
  float rx = ((a0.x + a1.x) + (a2.x + a3.x)) + ((a4.x + a5.x) + (a6.x + a7.x));
  float ry = ((a0.y + a1.y) + (a2.y + a3.y)) + ((a4.y + a5.y) + (a6.y + a7.y));
  float2 o;
  o.x = fmaxf(rx + b, 0.f);
  o.y = fmaxf(ry + b, 0.f);
  *(float2*)((char*)outT + (((size_t)d << 12) + ((size_t)col << 2))) = o;
}

extern "C" void kernel_launch(void* const* d_in, const int* in_sizes, int n_in,
                              void* d_out, int out_size, void* d_ws, size_t ws_size,
                              hipStream_t stream) {
  const float* x = (const float*)d_in[0];
  const int* src[3]    = {(const int*)d_in[1], (const int*)d_in[5], (const int*)d_in[9]};
  const int* dst[3]    = {(const int*)d_in[2], (const int*)d_in[6], (const int*)d_in[10]};
  const float* w[3]    = {(const float*)d_in[3], (const float*)d_in[7], (const float*)d_in[11]};
  const float* bias[3] = {(const float*)d_in[4], (const float*)d_in[8], (const float*)d_in[12]};
  float* out = (float*)d_out;

  // Workspace (~37 MB):
  //   buf0 @ 0            : 16 MB (xT, later h2T)
  //   buf1 @ 16 MB        : 16 MB (h1T, later outT)
  //   fillstart @ 32 MB   : 3*4096 ints
  //   rowptr @ +64 KB     : 3*4104 ints
  //   cntA   @ +128 KB    : 3*4096*16 ints (per-(row,chunk) counts/offsets)
  //   edges  @ +1 MB      : (2*EPAD01+EPAD2) int2, padded CSR
  char* ws = (char*)d_ws;
  float* buf0      = (float*)(ws);
  float* buf1      = (float*)(ws + (16u << 20));
  int*   fillstart = (int*)(ws + (32u << 20));
  int*   rowptr    = (int*)(ws + (32u << 20) + 65536u);
  int*   cntA      = (int*)(ws + (32u << 20) + 131072u);
  int2*  edges     = (int2*)(ws + (32u << 20) + (1u << 20));

  dim3 tb(32, 8);
  // x [1024][2048] -> buf0 = xT [2048][1024]
  transpose_kernel<<<dim3(2048 / 32, 1024 / 32), tb, 0, stream>>>(x, buf0, 1024, 2048);

  count_kernel<<<3 * C_CH, 256, 0, stream>>>(dst[0], dst[1], dst[2], cntA);
  scan_kernel<<<3, 1024, 0, stream>>>(cntA, rowptr, fillstart);
  scatter_kernel<<<3 * C_CH, 256, 0, stream>>>(
      src[0], dst[0], w[0], src[1], dst[1], w[1], src[2], dst[2], w[2], cntA, edges);
  padfill_kernel<<<12288 / 256, 256, 0, stream>>>(fillstart, rowptr, edges);

  // layer 0: buf0 (2048x1024) -> buf1 (4096x1024)
  spmm_kernel<<<(4096 / 2) * 8, 128, 0, stream>>>(buf0, edges, rowptr, bias[0], buf1);
  // layer 1: buf1 -> buf0 (4096x1024)
  spmm_kernel<<<(4096 / 2) * 8, 128, 0, stream>>>(buf1, edges + EPAD01, rowptr + 4104, bias[1], buf0);
  // layer 2: buf0 -> buf1 (1024x1024, outT)
  spmm_kernel<<<(1024 / 2) * 8, 128, 0, stream>>>(buf0, edges + 2 * EPAD01, rowptr + 2 * 4104, bias[2], buf1);

  // outT [1024 dst][1024 batch] -> d_out [batch][dst]
  transpose_kernel<<<dim3(1024 / 32, 1024 / 32), tb, 0, stream>>>(buf1, out, 1024, 1024);
}

// Round 9
// 191.524 us; speedup vs baseline: 1.3746x; 1.2596x over previous
//
#include <hip/hip_runtime.h>

#define E_EDGES 131072
// Layer dims: in {2048,4096,4096} -> out {4096,4096,1024}, batch 1024.
// Activations feature-major (hT[feat][1024]); CSR-by-dst built on device with
// no global atomics (LDS histogram -> scan -> LDS-cursor scatter).
// Rows padded to multiples of 16 (zero pads written by padfill_kernel).
// SpMM: 128-thread block = 2 waves = 2 dst rows x one 128-col chunk.
// KEY (r8 post-mortem): row index d is forced into an SGPR via
// readfirstlane so the edge-stream prefetch compiles to SCALAR loads
// (SMEM path, shared per wave) -- r6 proved this is worth ~50% (VGPR 28 vs
// 68, edge fetch off the VMEM pipe). 2-wave blocks double the WG-slot wave
// ceiling vs r6's 1-wave blocks (16 WG/CU x 2 = 32 waves/CU).
// chunk = blockIdx&7 -> XCD-resident input/output slices (2 MB each in L2).

#define EPAD01 196608   // capacity, layers 0,1 (4096 rows, E + 16*rows)
#define EPAD2  147456   // capacity, layer 2  (1024 rows)
#define C_CH   16       // chunks per layer (preprocessing)
#define CHUNK  (E_EDGES / C_CH)   // 8192 edges per chunk

typedef int iv4 __attribute__((ext_vector_type(4)));

__global__ void transpose_kernel(const float* __restrict__ in, float* __restrict__ out,
                                 int R, int C) {
  __shared__ float tile[32][33];
  int c0 = blockIdx.x << 5, r0 = blockIdx.y << 5;
  int tx = threadIdx.x, ty = threadIdx.y;  // 32 x 8
#pragma unroll
  for (int i = 0; i < 32; i += 8)
    tile[ty + i][tx] = in[(size_t)(r0 + ty + i) * C + (c0 + tx)];
  __syncthreads();
#pragma unroll
  for (int i = 0; i < 32; i += 8)
    out[(size_t)(c0 + ty + i) * R + (r0 + tx)] = tile[tx][ty + i];
}

// Phase A: per-(layer,chunk) LDS histogram of dst. bid = l*16 + c.
__global__ void __launch_bounds__(256) count_kernel(
    const int* __restrict__ d0, const int* __restrict__ d1, const int* __restrict__ d2,
    int* __restrict__ cntA) {
  int bid = blockIdx.x, l = bid >> 4, c = bid & 15;
  const int* dp = (l == 0) ? d0 : (l == 1) ? d1 : d2;
  __shared__ int hist[4096];
  for (int r = threadIdx.x; r < 4096; r += 256) hist[r] = 0;
  __syncthreads();
  int base = c * CHUNK;
  for (int i = 0; i < CHUNK; i += 256)
    atomicAdd(&hist[dp[base + i + threadIdx.x]], 1);
  __syncthreads();
  for (int r = threadIdx.x; r < 4096; r += 256)
    cntA[(((l << 12) + r) << 4) + c] = hist[r];  // layer2 rows>=1024 stay 0
}

// Phase B: per-layer (blockIdx = l) row totals -> padded row scan.
// rowptr[row] = padded row start; fillstart[row] = start + true count;
// cntA[row][c] rewritten to the chunk's start offset within the row.
__global__ void __launch_bounds__(1024) scan_kernel(int* __restrict__ cntA,
                                                    int* __restrict__ rowptr,
                                                    int* __restrict__ fillstart) {
  int l = blockIdx.x;
  int* rp = rowptr + l * 4104;
  int t = threadIdx.x;  // 1024 threads, 4 rows each
  int tot[4], pad[4];
  int local = 0;
  for (int i = 0; i < 4; ++i) {
    int row = (t << 2) + i;
    const int4* p = (const int4*)(cntA + (((l << 12) + row) << 4));
    int4 a = p[0], b = p[1], cc = p[2], dd = p[3];
    int s = a.x + a.y + a.z + a.w + b.x + b.y + b.z + b.w +
            cc.x + cc.y + cc.z + cc.w + dd.x + dd.y + dd.z + dd.w;
    tot[i] = s;
    pad[i] = (s + 15) & ~15;
    local += pad[i];
  }
  int lane = t & 63, wid = t >> 6;
  int incl = local;
  for (int off = 1; off < 64; off <<= 1) {
    int u = __shfl_up(incl, off, 64);
    if (lane >= off) incl += u;
  }
  __shared__ int wsum[16];
  if (lane == 63) wsum[wid] = incl;
  __syncthreads();
  if (t < 16) {
    int v = wsum[t];
    int iv = v;
    for (int off = 1; off < 16; off <<= 1) {
      int u = __shfl_up(iv, off, 16);
      if (t >= off) iv += u;
    }
    wsum[t] = iv - v;
  }
  __syncthreads();
  int run = wsum[wid] + (incl - local);
  for (int i = 0; i < 4; ++i) {
    int row = (t << 2) + i;
    rp[row] = run;
    fillstart[(l << 12) + row] = run + tot[i];
    int* p = cntA + (((l << 12) + row) << 4);
    int acc = run;
    for (int c = 0; c < 16; ++c) { int v = p[c]; p[c] = acc; acc += v; }
    run += pad[i];
  }
  if (t == 1023) rp[4096] = run;  // also covers rp[n] (rows past n are 0-count)
}

// Phase C: scatter with LDS cursors only. bid = l*16 + c.
__global__ void __launch_bounds__(256) scatter_kernel(
    const int* __restrict__ s0p, const int* __restrict__ d0p, const float* __restrict__ w0p,
    const int* __restrict__ s1p, const int* __restrict__ d1p, const float* __restrict__ w1p,
    const int* __restrict__ s2p, const int* __restrict__ d2p, const float* __restrict__ w2p,
    const int* __restrict__ cntA, int2* __restrict__ edges) {
  int bid = blockIdx.x, l = bid >> 4, c = bid & 15;
  const int* sp = (l == 0) ? s0p : (l == 1) ? s1p : s2p;
  const int* dp = (l == 0) ? d0p : (l == 1) ? d1p : d2p;
  const float* wp = (l == 0) ? w0p : (l == 1) ? w1p : w2p;
  int off = (l == 0) ? 0 : (l == 1) ? EPAD01 : 2 * EPAD01;
  __shared__ int cursor[4096];
  for (int r = threadIdx.x; r < 4096; r += 256)
    cursor[r] = cntA[(((l << 12) + r) << 4) + c];
  __syncthreads();
  int base = c * CHUNK;
  for (int i = 0; i < CHUNK; i += 256) {
    int e = base + i + threadIdx.x;
    int d = dp[e];
    int s = sp[e];
    float wv = wp[e];
    int pos = atomicAdd(&cursor[d], 1);
    edges[off + pos] = make_int2(s, __float_as_int(wv));
  }
}

// Zero the pad slots [fillstart[d], rowptr[d+1]) of every row (<= 15 per row).
__global__ void padfill_kernel(const int* __restrict__ fillstart,
                               const int* __restrict__ rowptr,
                               int2* __restrict__ edges) {
  int i = blockIdx.x * 256 + threadIdx.x;   // 0..12287
  int l = i >> 12, d = i & 4095;
  if (l == 2 && d >= 1024) return;
  int off = (l == 0) ? 0 : (l == 1) ? EPAD01 : 2 * EPAD01;
  int end = rowptr[l * 4104 + d + 1];
  int2 z = make_int2(0, 0);
  for (int p = fillstart[(l << 12) + d]; p < end; ++p) edges[off + p] = z;
}

#define LD2(IDX) (*(const float2*)(hb + ((size_t)(unsigned)(IDX) << 12)))
#define FMA2(A, WB, V) { float _w = __int_as_float(WB); \
  A.x = fmaf(_w, V.x, A.x); A.y = fmaf(_w, V.y, A.y); }

// SpMM gather: 128-thread block = 2 waves; wave w owns dst row 2*rg + w over
// one 128-col chunk (c = blockIdx&7 -> XCD c). d forced into SGPR via
// readfirstlane -> edge prefetch is scalar (SMEM path), gathers own VMEM.
__global__ void __launch_bounds__(128) spmm_kernel(const float* __restrict__ hT,
                                                   const int2* __restrict__ edges,
                                                   const int* __restrict__ rowptr,
                                                   const float* __restrict__ bias,
                                                   float* __restrict__ outT) {
  int c = blockIdx.x & 7;
  int rg = blockIdx.x >> 3;
  // wave id is wave-uniform by construction; readfirstlane makes it SGPR so
  // the compiler proves the edge pointer uniform (scalar loads, as in r6).
  int w = __builtin_amdgcn_readfirstlane(threadIdx.x >> 6);
  int lane = threadIdx.x & 63;
  int d = (rg << 1) + w;
  int col = (c << 7) + (lane << 1);
  const char* hb = (const char*)(hT + col);
  float2 a0 = {0, 0}, a1 = {0, 0}, a2 = {0, 0}, a3 = {0, 0};
  float2 a4 = {0, 0}, a5 = {0, 0}, a6 = {0, 0}, a7 = {0, 0};
  int s0 = rowptr[d], s1 = rowptr[d + 1];  // multiples of 16
  const iv4* ep = (const iv4*)(edges + s0);
  const iv4* ep_end = (const iv4*)(edges + s1);
  iv4 q0, q1, q2, q3, q4, q5, q6, q7;
  if (ep < ep_end) {
    q0 = ep[0]; q1 = ep[1]; q2 = ep[2]; q3 = ep[3];
    q4 = ep[4]; q5 = ep[5]; q6 = ep[6]; q7 = ep[7];
  }
  while (ep < ep_end) {
    iv4 p0 = q0, p1 = q1, p2 = q2, p3 = q3;
    iv4 p4 = q4, p5 = q5, p6 = q6, p7 = q7;
    ep += 8;
    if (ep < ep_end) {
      q0 = ep[0]; q1 = ep[1]; q2 = ep[2]; q3 = ep[3];
      q4 = ep[4]; q5 = ep[5]; q6 = ep[6]; q7 = ep[7];
    }
    float2 v0 = LD2(p0.x), v1 = LD2(p0.z), v2 = LD2(p1.x), v3 = LD2(p1.z);
    float2 v4 = LD2(p2.x), v5 = LD2(p2.z), v6 = LD2(p3.x), v7 = LD2(p3.z);
    float2 v8 = LD2(p4.x), v9 = LD2(p4.z), v10 = LD2(p5.x), v11 = LD2(p5.z);
    float2 v12 = LD2(p6.x), v13 = LD2(p6.z), v14 = LD2(p7.x), v15 = LD2(p7.z);
    FMA2(a0, p0.y, v0); FMA2(a1, p0.w, v1);
    FMA2(a2, p1.y, v2); FMA2(a3, p1.w, v3);
    FMA2(a4, p2.y, v4); FMA2(a5, p2.w, v5);
    FMA2(a6, p3.y, v6); FMA2(a7, p3.w, v7);
    FMA2(a0, p4.y, v8); FMA2(a1, p4.w, v9);
    FMA2(a2, p5.y, v10); FMA2(a3, p5.w, v11);
    FMA2(a4, p6.y, v12); FMA2(a5, p6.w, v13);
    FMA2(a6, p7.y, v14); FMA2(a7, p7.w, v15);
  }
  float b = bias[d];
  float rx = ((a0.x + a1.x) + (a2.x + a3.x)) + ((a4.x + a5.x) + (a6.x + a7.x));
  float ry = ((a0.y + a1.y) + (a2.y + a3.y)) + ((a4.y + a5.y) + (a6.y + a7.y));
  float2 o;
  o.x = fmaxf(rx + b, 0.f);
  o.y = fmaxf(ry + b, 0.f);
  *(float2*)((char*)outT + (((size_t)d << 12) + ((size_t)col << 2))) = o;
}

extern "C" void kernel_launch(void* const* d_in, const int* in_sizes, int n_in,
                              void* d_out, int out_size, void* d_ws, size_t ws_size,
                              hipStream_t stream) {
  const float* x = (const float*)d_in[0];
  const int* src[3]    = {(const int*)d_in[1], (const int*)d_in[5], (const int*)d_in[9]};
  const int* dst[3]    = {(const int*)d_in[2], (const int*)d_in[6], (const int*)d_in[10]};
  const float* w[3]    = {(const float*)d_in[3], (const float*)d_in[7], (const float*)d_in[11]};
  const float* bias[3] = {(const float*)d_in[4], (const float*)d_in[8], (const float*)d_in[12]};
  float* out = (float*)d_out;

  // Workspace (~37 MB):
  //   buf0 @ 0            : 16 MB (xT, later h2T)
  //   buf1 @ 16 MB        : 16 MB (h1T, later outT)
  //   fillstart @ 32 MB   : 3*4096 ints
  //   rowptr @ +64 KB     : 3*4104 ints
  //   cntA   @ +128 KB    : 3*4096*16 ints (per-(row,chunk) counts/offsets)
  //   edges  @ +1 MB      : (2*EPAD01+EPAD2) int2, padded CSR
  char* ws = (char*)d_ws;
  float* buf0      = (float*)(ws);
  float* buf1      = (float*)(ws + (16u << 20));
  int*   fillstart = (int*)(ws + (32u << 20));
  int*   rowptr    = (int*)(ws + (32u << 20) + 65536u);
  int*   cntA      = (int*)(ws + (32u << 20) + 131072u);
  int2*  edges     = (int2*)(ws + (32u << 20) + (1u << 20));

  dim3 tb(32, 8);
  // x [1024][2048] -> buf0 = xT [2048][1024]
  transpose_kernel<<<dim3(2048 / 32, 1024 / 32), tb, 0, stream>>>(x, buf0, 1024, 2048);

  count_kernel<<<3 * C_CH, 256, 0, stream>>>(dst[0], dst[1], dst[2], cntA);
  scan_kernel<<<3, 1024, 0, stream>>>(cntA, rowptr, fillstart);
  scatter_kernel<<<3 * C_CH, 256, 0, stream>>>(
      src[0], dst[0], w[0], src[1], dst[1], w[1], src[2], dst[2], w[2], cntA, edges);
  padfill_kernel<<<12288 / 256, 256, 0, stream>>>(fillstart, rowptr, edges);

  // layer 0: buf0 (2048x1024) -> buf1 (4096x1024)
  spmm_kernel<<<(4096 / 2) * 8, 128, 0, stream>>>(buf0, edges, rowptr, bias[0], buf1);
  // layer 1: buf1 -> buf0 (4096x1024)
  spmm_kernel<<<(4096 / 2) * 8, 128, 0, stream>>>(buf1, edges + EPAD01, rowptr + 4104, bias[1], buf0);
  // layer 2: buf0 -> buf1 (1024x1024, outT)
  spmm_kernel<<<(1024 / 2) * 8, 128, 0, stream>>>(buf0, edges + 2 * EPAD01, rowptr + 2 * 4104, bias[2], buf1);

  // outT [1024 dst][1024 batch] -> d_out [batch][dst]
  transpose_kernel<<<dim3(1024 / 32, 1024 / 32), tb, 0, stream>>>(buf1, out, 1024, 1024);
}

// Round 10
// 150.564 us; speedup vs baseline: 1.7486x; 1.2720x over previous
//
#include <hip/hip_runtime.h>

#define E_EDGES 131072
// Layer dims: in {2048,4096,4096} -> out {4096,4096,1024}, batch 1024.
// Activations feature-major (hT[feat][1024]); CSR-by-dst built on device with
// no global atomics (LDS histogram -> scan -> LDS-cursor scatter).
// Rows padded to multiples of 8 (zero pads written by padfill_kernel).
// SpMM: 128-thread block = 2 waves = 2 dst rows x one 256-col chunk (float4
// per lane -> 1 KB per gather instruction, half the VMEM instructions of r9's
// float2 version at identical logical traffic). Edge stream scalar via
// readfirstlane'd wave id (r9-verified: VGPR 28 / SGPR 96 codegen).
// This round is a discriminator: if spmm stays ~43 us the gathers are
// L3-BW-bound (11.9 TB/s) and the structure is at its roofline; if it drops
// ~2x they were VMEM-issue-bound.

#define EPAD01 163840   // capacity, layers 0,1 (4096 rows, E + 8*rows)
#define EPAD2  139264   // capacity, layer 2  (1024 rows)
#define C_CH   16       // chunks per layer (preprocessing)
#define CHUNK  (E_EDGES / C_CH)   // 8192 edges per chunk

typedef int iv4 __attribute__((ext_vector_type(4)));

__global__ void transpose_kernel(const float* __restrict__ in, float* __restrict__ out,
                                 int R, int C) {
  __shared__ float tile[32][33];
  int c0 = blockIdx.x << 5, r0 = blockIdx.y << 5;
  int tx = threadIdx.x, ty = threadIdx.y;  // 32 x 8
#pragma unroll
  for (int i = 0; i < 32; i += 8)
    tile[ty + i][tx] = in[(size_t)(r0 + ty + i) * C + (c0 + tx)];
  __syncthreads();
#pragma unroll
  for (int i = 0; i < 32; i += 8)
    out[(size_t)(c0 + ty + i) * R + (r0 + tx)] = tile[tx][ty + i];
}

// Phase A: per-(layer,chunk) LDS histogram of dst. bid = l*16 + c.
__global__ void __launch_bounds__(256) count_kernel(
    const int* __restrict__ d0, const int* __restrict__ d1, const int* __restrict__ d2,
    int* __restrict__ cntA) {
  int bid = blockIdx.x, l = bid >> 4, c = bid & 15;
  const int* dp = (l == 0) ? d0 : (l == 1) ? d1 : d2;
  __shared__ int hist[4096];
  for (int r = threadIdx.x; r < 4096; r += 256) hist[r] = 0;
  __syncthreads();
  int base = c * CHUNK;
  for (int i = 0; i < CHUNK; i += 256)
    atomicAdd(&hist[dp[base + i + threadIdx.x]], 1);
  __syncthreads();
  for (int r = threadIdx.x; r < 4096; r += 256)
    cntA[(((l << 12) + r) << 4) + c] = hist[r];  // layer2 rows>=1024 stay 0
}

// Phase B: per-layer (blockIdx = l) row totals -> padded row scan.
// rowptr[row] = padded row start; fillstart[row] = start + true count;
// cntA[row][c] rewritten to the chunk's start offset within the row.
__global__ void __launch_bounds__(1024) scan_kernel(int* __restrict__ cntA,
                                                    int* __restrict__ rowptr,
                                                    int* __restrict__ fillstart) {
  int l = blockIdx.x;
  int* rp = rowptr + l * 4104;
  int t = threadIdx.x;  // 1024 threads, 4 rows each
  int tot[4], pad[4];
  int local = 0;
  for (int i = 0; i < 4; ++i) {
    int row = (t << 2) + i;
    const int4* p = (const int4*)(cntA + (((l << 12) + row) << 4));
    int4 a = p[0], b = p[1], cc = p[2], dd = p[3];
    int s = a.x + a.y + a.z + a.w + b.x + b.y + b.z + b.w +
            cc.x + cc.y + cc.z + cc.w + dd.x + dd.y + dd.z + dd.w;
    tot[i] = s;
    pad[i] = (s + 7) & ~7;   // pad row to multiple of 8 (8-edge unroll)
    local += pad[i];
  }
  int lane = t & 63, wid = t >> 6;
  int incl = local;
  for (int off = 1; off < 64; off <<= 1) {
    int u = __shfl_up(incl, off, 64);
    if (lane >= off) incl += u;
  }
  __shared__ int wsum[16];
  if (lane == 63) wsum[wid] = incl;
  __syncthreads();
  if (t < 16) {
    int v = wsum[t];
    int iv = v;
    for (int off = 1; off < 16; off <<= 1) {
      int u = __shfl_up(iv, off, 16);
      if (t >= off) iv += u;
    }
    wsum[t] = iv - v;
  }
  __syncthreads();
  int run = wsum[wid] + (incl - local);
  for (int i = 0; i < 4; ++i) {
    int row = (t << 2) + i;
    rp[row] = run;
    fillstart[(l << 12) + row] = run + tot[i];
    int* p = cntA + (((l << 12) + row) << 4);
    int acc = run;
    for (int c = 0; c < 16; ++c) { int v = p[c]; p[c] = acc; acc += v; }
    run += pad[i];
  }
  if (t == 1023) rp[4096] = run;  // also covers rp[n] (rows past n are 0-count)
}

// Phase C: scatter with LDS cursors only. bid = l*16 + c.
__global__ void __launch_bounds__(256) scatter_kernel(
    const int* __restrict__ s0p, const int* __restrict__ d0p, const float* __restrict__ w0p,
    const int* __restrict__ s1p, const int* __restrict__ d1p, const float* __restrict__ w1p,
    const int* __restrict__ s2p, const int* __restrict__ d2p, const float* __restrict__ w2p,
    const int* __restrict__ cntA, int2* __restrict__ edges) {
  int bid = blockIdx.x, l = bid >> 4, c = bid & 15;
  const int* sp = (l == 0) ? s0p : (l == 1) ? s1p : s2p;
  const int* dp = (l == 0) ? d0p : (l == 1) ? d1p : d2p;
  const float* wp = (l == 0) ? w0p : (l == 1) ? w1p : w2p;
  int off = (l == 0) ? 0 : (l == 1) ? EPAD01 : 2 * EPAD01;
  __shared__ int cursor[4096];
  for (int r = threadIdx.x; r < 4096; r += 256)
    cursor[r] = cntA[(((l << 12) + r) << 4) + c];
  __syncthreads();
  int base = c * CHUNK;
  for (int i = 0; i < CHUNK; i += 256) {
    int e = base + i + threadIdx.x;
    int d = dp[e];
    int s = sp[e];
    float wv = wp[e];
    int pos = atomicAdd(&cursor[d], 1);
    edges[off + pos] = make_int2(s, __float_as_int(wv));
  }
}

// Zero the pad slots [fillstart[d], rowptr[d+1]) of every row (<= 7 per row).
__global__ void padfill_kernel(const int* __restrict__ fillstart,
                               const int* __restrict__ rowptr,
                               int2* __restrict__ edges) {
  int i = blockIdx.x * 256 + threadIdx.x;   // 0..12287
  int l = i >> 12, d = i & 4095;
  if (l == 2 && d >= 1024) return;
  int off = (l == 0) ? 0 : (l == 1) ? EPAD01 : 2 * EPAD01;
  int end = rowptr[l * 4104 + d + 1];
  int2 z = make_int2(0, 0);
  for (int p = fillstart[(l << 12) + d]; p < end; ++p) edges[off + p] = z;
}

#define LD4(IDX) (*(const float4*)(hb + ((size_t)(unsigned)(IDX) << 12)))
#define FMA4(A, WB, V) { float _w = __int_as_float(WB); \
  A.x = fmaf(_w, V.x, A.x); A.y = fmaf(_w, V.y, A.y); \
  A.z = fmaf(_w, V.z, A.z); A.w = fmaf(_w, V.w, A.w); }

// SpMM gather: 128-thread block = 2 waves; wave w owns dst row 2*rg + w over
// one 256-col chunk (c = blockIdx&3). float4 per lane -> 1 KB per gather
// instruction, 8 gathers (8 KB) in flight; edge stream scalar-prefetched.
__global__ void __launch_bounds__(128) spmm_kernel(const float* __restrict__ hT,
                                                   const int2* __restrict__ edges,
                                                   const int* __restrict__ rowptr,
                                                   const float* __restrict__ bias,
                                                   float* __restrict__ outT) {
  int c = blockIdx.x & 3;
  int rg = blockIdx.x >> 2;
  // wave id is wave-uniform; readfirstlane -> SGPR -> scalar edge loads (r9).
  int w = __builtin_amdgcn_readfirstlane(threadIdx.x >> 6);
  int lane = threadIdx.x & 63;
  int d = (rg << 1) + w;
  int col = (c << 8) + (lane << 2);
  const char* hb = (const char*)(hT + col);
  float4 a0 = {0, 0, 0, 0}, a1 = {0, 0, 0, 0}, a2 = {0, 0, 0, 0}, a3 = {0, 0, 0, 0};
  float4 a4 = {0, 0, 0, 0}, a5 = {0, 0, 0, 0}, a6 = {0, 0, 0, 0}, a7 = {0, 0, 0, 0};
  int s0 = rowptr[d], s1 = rowptr[d + 1];  // multiples of 8
  const iv4* ep = (const iv4*)(edges + s0);
  const iv4* ep_end = (const iv4*)(edges + s1);
  iv4 q0, q1, q2, q3;
  if (ep < ep_end) { q0 = ep[0]; q1 = ep[1]; q2 = ep[2]; q3 = ep[3]; }
  while (ep < ep_end) {
    iv4 p0 = q0, p1 = q1, p2 = q2, p3 = q3;
    ep += 4;
    if (ep < ep_end) { q0 = ep[0]; q1 = ep[1]; q2 = ep[2]; q3 = ep[3]; }
    float4 v0 = LD4(p0.x), v1 = LD4(p0.z), v2 = LD4(p1.x), v3 = LD4(p1.z);
    float4 v4 = LD4(p2.x), v5 = LD4(p2.z), v6 = LD4(p3.x), v7 = LD4(p3.z);
    FMA4(a0, p0.y, v0); FMA4(a1, p0.w, v1);
    FMA4(a2, p1.y, v2); FMA4(a3, p1.w, v3);
    FMA4(a4, p2.y, v4); FMA4(a5, p2.w, v5);
    FMA4(a6, p3.y, v6); FMA4(a7, p3.w, v7);
  }
  float b = bias[d];
  float4 o;
  o.x = fmaxf(((a0.x + a1.x) + (a2.x + a3.x)) + ((a4.x + a5.x) + (a6.x + a7.x)) + b, 0.f);
  o.y = fmaxf(((a0.y + a1.y) + (a2.y + a3.y)) + ((a4.y + a5.y) + (a6.y + a7.y)) + b, 0.f);
  o.z = fmaxf(((a0.z + a1.z) + (a2.z + a3.z)) + ((a4.z + a5.z) + (a6.z + a7.z)) + b, 0.f);
  o.w = fmaxf(((a0.w + a1.w) + (a2.w + a3.w)) + ((a4.w + a5.w) + (a6.w + a7.w)) + b, 0.f);
  *(float4*)((char*)outT + (((size_t)d << 12) + ((size_t)col << 2))) = o;
}

extern "C" void kernel_launch(void* const* d_in, const int* in_sizes, int n_in,
                              void* d_out, int out_size, void* d_ws, size_t ws_size,
                              hipStream_t stream) {
  const float* x = (const float*)d_in[0];
  const int* src[3]    = {(const int*)d_in[1], (const int*)d_in[5], (const int*)d_in[9]};
  const int* dst[3]    = {(const int*)d_in[2], (const int*)d_in[6], (const int*)d_in[10]};
  const float* w[3]    = {(const float*)d_in[3], (const float*)d_in[7], (const float*)d_in[11]};
  const float* bias[3] = {(const float*)d_in[4], (const float*)d_in[8], (const float*)d_in[12]};
  float* out = (float*)d_out;

  // Workspace (~37 MB):
  //   buf0 @ 0            : 16 MB (xT, later h2T)
  //   buf1 @ 16 MB        : 16 MB (h1T, later outT)
  //   fillstart @ 32 MB   : 3*4096 ints
  //   rowptr @ +64 KB     : 3*4104 ints
  //   cntA   @ +128 KB    : 3*4096*16 ints (per-(row,chunk) counts/offsets)
  //   edges  @ +1 MB      : (2*EPAD01+EPAD2) int2, padded CSR
  char* ws = (char*)d_ws;
  float* buf0      = (float*)(ws);
  float* buf1      = (float*)(ws + (16u << 20));
  int*   fillstart = (int*)(ws + (32u << 20));
  int*   rowptr    = (int*)(ws + (32u << 20) + 65536u);
  int*   cntA      = (int*)(ws + (32u << 20) + 131072u);
  int2*  edges     = (int2*)(ws + (32u << 20) + (1u << 20));

  dim3 tb(32, 8);
  // x [1024][2048] -> buf0 = xT [2048][1024]
  transpose_kernel<<<dim3(2048 / 32, 1024 / 32), tb, 0, stream>>>(x, buf0, 1024, 2048);

  count_kernel<<<3 * C_CH, 256, 0, stream>>>(dst[0], dst[1], dst[2], cntA);
  scan_kernel<<<3, 1024, 0, stream>>>(cntA, rowptr, fillstart);
  scatter_kernel<<<3 * C_CH, 256, 0, stream>>>(
      src[0], dst[0], w[0], src[1], dst[1], w[1], src[2], dst[2], w[2], cntA, edges);
  padfill_kernel<<<12288 / 256, 256, 0, stream>>>(fillstart, rowptr, edges);

  // layer 0: buf0 (2048x1024) -> buf1 (4096x1024)
  spmm_kernel<<<(4096 / 2) * 4, 128, 0, stream>>>(buf0, edges, rowptr, bias[0], buf1);
  // layer 1: buf1 -> buf0 (4096x1024)
  spmm_kernel<<<(4096 / 2) * 4, 128, 0, stream>>>(buf1, edges + EPAD01, rowptr + 4104, bias[1], buf0);
  // layer 2: buf0 -> buf1 (1024x1024, outT)
  spmm_kernel<<<(1024 / 2) * 4, 128, 0, stream>>>(buf0, edges + 2 * EPAD01, rowptr + 2 * 4104, bias[2], buf1);

  // outT [1024 dst][1024 batch] -> d_out [batch][dst]
  transpose_kernel<<<dim3(1024 / 32, 1024 / 32), tb, 0, stream>>>(buf1, out, 1024, 1024);
}

// Round 11
// 149.927 us; speedup vs baseline: 1.7560x; 1.0042x over previous
//
#include <hip/hip_runtime.h>

#define E_EDGES 131072
// Layer dims: in {2048,4096,4096} -> out {4096,4096,1024}, batch 1024.
// Activations feature-major (hT[feat][1024]); CSR-by-dst built on device with
// no global atomics (LDS histogram -> scan -> LDS-cursor scatter).
// Rows padded to multiples of 8 (zero pads written inline by scan_kernel).
// SpMM v2 (streaming): each wave owns rpw consecutive dst rows and walks
// their contiguous padded CSR range as ONE continuous edge stream (scalar
// prefetch never drains across row boundaries); flush = bias+relu+store when
// the 8-edge group boundary equals rowptr[r+1]. float4 gathers, 256-col
// chunks, c = blockIdx&3. r10 discriminator: gathers are issue/latency-bound
// -> longer-lived blocks + no per-row prologue is the remaining lever.

#define EPAD01 163840   // capacity, layers 0,1 (4096 rows, E + 8*rows)
#define EPAD2  139264   // capacity, layer 2  (1024 rows)
#define C_CH   16       // chunks per layer (preprocessing)
#define CHUNK  (E_EDGES / C_CH)   // 8192 edges per chunk

typedef int iv4 __attribute__((ext_vector_type(4)));

// K1: fused transpose of x (blocks 0..2047) + dst histogram (blocks 2048..2095).
__global__ void __launch_bounds__(256) fused_tp_count_kernel(
    const float* __restrict__ x, float* __restrict__ xT,
    const int* __restrict__ d0, const int* __restrict__ d1, const int* __restrict__ d2,
    int* __restrict__ cntA) {
  __shared__ int sh[4096];
  int bid = blockIdx.x;
  int t = threadIdx.x;
  if (bid < 2048) {
    // transpose x [1024][2048] -> xT [2048][1024], 32x32 tiles
    float (*tile)[33] = (float(*)[33])sh;
    int c0 = (bid & 63) << 5, r0 = (bid >> 6) << 5;
    int tx = t & 31, ty = t >> 5;  // 32 x 8
#pragma unroll
    for (int i = 0; i < 32; i += 8)
      tile[ty + i][tx] = x[(size_t)(r0 + ty + i) * 2048 + (c0 + tx)];
    __syncthreads();
#pragma unroll
    for (int i = 0; i < 32; i += 8)
      xT[(size_t)(c0 + ty + i) * 1024 + (r0 + tx)] = tile[tx][ty + i];
  } else {
    int bid2 = bid - 2048, l = bid2 >> 4, c = bid2 & 15;
    const int* dp = (l == 0) ? d0 : (l == 1) ? d1 : d2;
    for (int r = t; r < 4096; r += 256) sh[r] = 0;
    __syncthreads();
    int base = c * CHUNK;
    for (int i = 0; i < CHUNK; i += 256)
      atomicAdd(&sh[dp[base + i + t]], 1);
    __syncthreads();
    for (int r = t; r < 4096; r += 256)
      cntA[(((l << 12) + r) << 4) + c] = sh[r];  // layer2 rows>=1024 stay 0
  }
}

// K2: per-layer (blockIdx = l) padded row scan + inline pad-slot zeroing.
// rowptr[row] = padded row start; cntA[row][c] -> chunk start offsets.
__global__ void __launch_bounds__(1024) scan_kernel(int* __restrict__ cntA,
                                                    int* __restrict__ rowptr,
                                                    int2* __restrict__ edges) {
  int l = blockIdx.x;
  int* rp = rowptr + l * 4104;
  int off = (l == 0) ? 0 : (l == 1) ? EPAD01 : 2 * EPAD01;
  int t = threadIdx.x;  // 1024 threads, 4 rows each
  int tot[4], pad[4];
  int local = 0;
  for (int i = 0; i < 4; ++i) {
    int row = (t << 2) + i;
    const int4* p = (const int4*)(cntA + (((l << 12) + row) << 4));
    int4 a = p[0], b = p[1], cc = p[2], dd = p[3];
    int s = a.x + a.y + a.z + a.w + b.x + b.y + b.z + b.w +
            cc.x + cc.y + cc.z + cc.w + dd.x + dd.y + dd.z + dd.w;
    tot[i] = s;
    pad[i] = (s + 7) & ~7;   // pad row to multiple of 8 (8-edge groups)
    local += pad[i];
  }
  int lane = t & 63, wid = t >> 6;
  int incl = local;
  for (int o = 1; o < 64; o <<= 1) {
    int u = __shfl_up(incl, o, 64);
    if (lane >= o) incl += u;
  }
  __shared__ int wsum[16];
  if (lane == 63) wsum[wid] = incl;
  __syncthreads();
  if (t < 16) {
    int v = wsum[t];
    int iv = v;
    for (int o = 1; o < 16; o <<= 1) {
      int u = __shfl_up(iv, o, 16);
      if (t >= o) iv += u;
    }
    wsum[t] = iv - v;
  }
  __syncthreads();
  int run = wsum[wid] + (incl - local);
  int2 z = make_int2(0, 0);
  for (int i = 0; i < 4; ++i) {
    int row = (t << 2) + i;
    rp[row] = run;
    int* p = cntA + (((l << 12) + row) << 4);
    int acc = run;
    for (int c = 0; c < 16; ++c) { int v = p[c]; p[c] = acc; acc += v; }
    for (int q = run + tot[i]; q < run + pad[i]; ++q) edges[off + q] = z;  // pads
    run += pad[i];
  }
  if (t == 1023) rp[4096] = run;  // rows past n are 0-count; also covers rp[n]
}

// K3: scatter with LDS cursors only. bid = l*16 + c.
__global__ void __launch_bounds__(256) scatter_kernel(
    const int* __restrict__ s0p, const int* __restrict__ d0p, const float* __restrict__ w0p,
    const int* __restrict__ s1p, const int* __restrict__ d1p, const float* __restrict__ w1p,
    const int* __restrict__ s2p, const int* __restrict__ d2p, const float* __restrict__ w2p,
    const int* __restrict__ cntA, int2* __restrict__ edges) {
  int bid = blockIdx.x, l = bid >> 4, c = bid & 15;
  const int* sp = (l == 0) ? s0p : (l == 1) ? s1p : s2p;
  const int* dp = (l == 0) ? d0p : (l == 1) ? d1p : d2p;
  const float* wp = (l == 0) ? w0p : (l == 1) ? w1p : w2p;
  int off = (l == 0) ? 0 : (l == 1) ? EPAD01 : 2 * EPAD01;
  __shared__ int cursor[4096];
  for (int r = threadIdx.x; r < 4096; r += 256)
    cursor[r] = cntA[(((l << 12) + r) << 4) + c];
  __syncthreads();
  int base = c * CHUNK;
  for (int i = 0; i < CHUNK; i += 256) {
    int e = base + i + threadIdx.x;
    int d = dp[e];
    int s = sp[e];
    float wv = wp[e];
    int pos = atomicAdd(&cursor[d], 1);
    edges[off + pos] = make_int2(s, __float_as_int(wv));
  }
}

#define LD4(IDX) (*(const float4*)(hb + ((size_t)(unsigned)(IDX) << 12)))
#define FMA4(A, WB, V) { float _w = __int_as_float(WB); \
  A.x = fmaf(_w, V.x, A.x); A.y = fmaf(_w, V.y, A.y); \
  A.z = fmaf(_w, V.z, A.z); A.w = fmaf(_w, V.w, A.w); }
#define STORE_ROW(RR, O) *(float4*)((char*)outT + (((size_t)(RR) << 12) + ((size_t)col << 2))) = (O)

// SpMM v2: 128-thread block = 2 waves; wave owns rpw consecutive rows and
// streams their contiguous padded edge range (groups of 8; rows padded to 8
// so groups never straddle rows). Edge metadata scalar (readfirstlane'd wave
// id -> uniform addresses); 8 float4 gathers in flight continuously.
__global__ void __launch_bounds__(128) spmm_kernel(const float* __restrict__ hT,
                                                   const int2* __restrict__ edges,
                                                   const int* __restrict__ rowptr,
                                                   const float* __restrict__ bias,
                                                   float* __restrict__ outT,
                                                   int rpw) {
  int c = blockIdx.x & 3;
  int rg = blockIdx.x >> 2;
  int w = __builtin_amdgcn_readfirstlane(threadIdx.x >> 6);
  int lane = threadIdx.x & 63;
  int r = (rg * 2 + w) * rpw;
  int rlim = r + rpw;
  int col = (c << 8) + (lane << 2);
  const char* hb = (const char*)(hT + col);

  int e = rowptr[r];
  int e_last = rowptr[rlim];
  int r_end = 0;
  // skip leading empty rows (bias-only output); ~never happens but must be correct
  for (;;) {
    if (r >= rlim) break;
    r_end = rowptr[r + 1];
    if (r_end != e) break;
    float bb = bias[r];
    float4 o; o.x = o.y = o.z = o.w = fmaxf(bb, 0.f);
    STORE_ROW(r, o);
    ++r;
  }
  if (e >= e_last) return;

  const iv4* ep = (const iv4*)(edges + e);
  iv4 q0 = ep[0], q1 = ep[1], q2 = ep[2], q3 = ep[3];
  float4 a0 = {0.f, 0.f, 0.f, 0.f}, a1 = {0.f, 0.f, 0.f, 0.f};
  while (e < e_last) {
    iv4 p0 = q0, p1 = q1, p2 = q2, p3 = q3;
    ep += 4;
    // prefetch next group; may read <=32B past e_last, inside edges capacity
    q0 = ep[0]; q1 = ep[1]; q2 = ep[2]; q3 = ep[3];
    float4 v0 = LD4(p0.x), v1 = LD4(p0.z), v2 = LD4(p1.x), v3 = LD4(p1.z);
    float4 v4 = LD4(p2.x), v5 = LD4(p2.z), v6 = LD4(p3.x), v7 = LD4(p3.z);
    FMA4(a0, p0.y, v0); FMA4(a1, p0.w, v1);
    FMA4(a0, p1.y, v2); FMA4(a1, p1.w, v3);
    FMA4(a0, p2.y, v4); FMA4(a1, p2.w, v5);
    FMA4(a0, p3.y, v6); FMA4(a1, p3.w, v7);
    e += 8;
    if (e == r_end) {   // group boundary == row boundary (rows padded to 8)
      float bb = bias[r];
      float4 o;
      o.x = fmaxf((a0.x + a1.x) + bb, 0.f);
      o.y = fmaxf((a0.y + a1.y) + bb, 0.f);
      o.z = fmaxf((a0.z + a1.z) + bb, 0.f);
      o.w = fmaxf((a0.w + a1.w) + bb, 0.f);
      STORE_ROW(r, o);
      a0.x = a0.y = a0.z = a0.w = 0.f;
      a1.x = a1.y = a1.z = a1.w = 0.f;
      ++r;
      for (;;) {
        if (r >= rlim) break;
        r_end = rowptr[r + 1];
        if (r_end != e) break;
        float b2 = bias[r];
        float4 o2; o2.x = o2.y = o2.z = o2.w = fmaxf(b2, 0.f);
        STORE_ROW(r, o2);
        ++r;
      }
    }
  }
}

__global__ void transpose_kernel(const float* __restrict__ in, float* __restrict__ out,
                                 int R, int C) {
  __shared__ float tile[32][33];
  int c0 = blockIdx.x << 5, r0 = blockIdx.y << 5;
  int tx = threadIdx.x, ty = threadIdx.y;  // 32 x 8
#pragma unroll
  for (int i = 0; i < 32; i += 8)
    tile[ty + i][tx] = in[(size_t)(r0 + ty + i) * C + (c0 + tx)];
  __syncthreads();
#pragma unroll
  for (int i = 0; i < 32; i += 8)
    out[(size_t)(c0 + ty + i) * R + (r0 + tx)] = tile[tx][ty + i];
}

extern "C" void kernel_launch(void* const* d_in, const int* in_sizes, int n_in,
                              void* d_out, int out_size, void* d_ws, size_t ws_size,
                              hipStream_t stream) {
  const float* x = (const float*)d_in[0];
  const int* src[3]    = {(const int*)d_in[1], (const int*)d_in[5], (const int*)d_in[9]};
  const int* dst[3]    = {(const int*)d_in[2], (const int*)d_in[6], (const int*)d_in[10]};
  const float* w[3]    = {(const float*)d_in[3], (const float*)d_in[7], (const float*)d_in[11]};
  const float* bias[3] = {(const float*)d_in[4], (const float*)d_in[8], (const float*)d_in[12]};
  float* out = (float*)d_out;

  // Workspace (~36.8 MB):
  //   buf0 @ 0          : 16 MB (xT, later h2T)
  //   buf1 @ 16 MB      : 16 MB (h1T, later outT)
  //   rowptr @ 32 MB    : 3*4104 ints
  //   cntA @ +64 KB     : 3*4096*16 ints (per-(row,chunk) counts/offsets)
  //   edges @ 33 MB     : (2*EPAD01+EPAD2) int2, padded CSR
  char* ws = (char*)d_ws;
  float* buf0   = (float*)(ws);
  float* buf1   = (float*)(ws + (16u << 20));
  int*   rowptr = (int*)(ws + (32u << 20));
  int*   cntA   = (int*)(ws + (32u << 20) + 65536u);
  int2*  edges  = (int2*)(ws + (33u << 20));

  // K1: transpose x -> buf0 (xT) + dst histograms
  fused_tp_count_kernel<<<2048 + 3 * C_CH, 256, 0, stream>>>(
      x, buf0, dst[0], dst[1], dst[2], cntA);
  // K2: padded scan + inline pad zeroing
  scan_kernel<<<3, 1024, 0, stream>>>(cntA, rowptr, edges);
  // K3: CSR scatter
  scatter_kernel<<<3 * C_CH, 256, 0, stream>>>(
      src[0], dst[0], w[0], src[1], dst[1], w[1], src[2], dst[2], w[2], cntA, edges);

  // layer 0: buf0 (2048x1024) -> buf1 (4096x1024), 2 rows/wave
  spmm_kernel<<<(4096 / 4) * 4, 128, 0, stream>>>(buf0, edges, rowptr, bias[0], buf1, 2);
  // layer 1: buf1 -> buf0 (4096x1024), 2 rows/wave
  spmm_kernel<<<(4096 / 4) * 4, 128, 0, stream>>>(buf1, edges + EPAD01, rowptr + 4104, bias[1], buf0, 2);
  // layer 2: buf0 -> buf1 (1024x1024, outT), 1 row/wave
  spmm_kernel<<<(1024 / 2) * 4, 128, 0, stream>>>(buf0, edges + 2 * EPAD01, rowptr + 2 * 4104, bias[2], buf1, 1);

  // outT [1024 dst][1024 batch] -> d_out [batch][dst]
  transpose_kernel<<<dim3(1024 / 32, 1024 / 32), dim3(32, 8), 0, stream>>>(buf1, out, 1024, 1024);
}